// Round 1
// baseline (942.507 us; speedup 1.0000x reference)
//
#include <hip/hip_runtime.h>
#include <math.h>

// ---------------------------------------------------------------------------
// GCN pipeline: conv1(relu) -> conv2(relu) -> quantize(+reg) -> add -> conv3
// All fp32 (argmax in quantize is tie-sensitive; bf16 upstream would flip it).
// ---------------------------------------------------------------------------

// ---------------- CSR build ----------------

__global__ void k_init(int* cnt, int* cursor, int* counter, float* balance, int n) {
    int i = blockIdx.x * blockDim.x + threadIdx.x;
    if (i < n) { cnt[i] = 0; cursor[i] = 0; }
    if (i < 480) balance[i] = 0.f;
    if (i == 0) *counter = 0;
}

__global__ void k_count(const int* __restrict__ dst, int* __restrict__ cnt, int e) {
    int i = blockIdx.x * blockDim.x + threadIdx.x;
    if (i < e) atomicAdd(&cnt[dst[i]], 1);
}

__global__ void k_dinv(const int* __restrict__ cnt, float* __restrict__ dinv, int n) {
    int i = blockIdx.x * blockDim.x + threadIdx.x;
    if (i < n) dinv[i] = rsqrtf((float)cnt[i] + 1.0f);   // +1 self loop
}

__global__ void k_alloc(const int* __restrict__ cnt, int* __restrict__ row_start,
                        int* __restrict__ counter, int n) {
    int i = blockIdx.x * blockDim.x + threadIdx.x;
    if (i < n) row_start[i] = atomicAdd(counter, cnt[i]);
}

__global__ void k_fill(const int* __restrict__ src, const int* __restrict__ dst,
                       const float* __restrict__ dinv, const int* __restrict__ row_start,
                       int* __restrict__ cursor, int* __restrict__ csr_src,
                       float* __restrict__ csr_norm, int e) {
    int i = blockIdx.x * blockDim.x + threadIdx.x;
    if (i >= e) return;
    int s = src[i], d = dst[i];
    int slot = atomicAdd(&cursor[d], 1);
    int idx = row_start[d] + slot;
    csr_src[idx] = s;
    csr_norm[idx] = dinv[s] * dinv[d];
}

// ---------------- fp32 GEMM: C[M,N] = A[M,K] @ B[K,N] ----------------
// 128x128 tile, BK=32, 256 threads, 8x8 per thread (split 4+4 rows/cols).

__global__ __launch_bounds__(256, 2) void k_gemm(const float* __restrict__ A,
                                                 const float* __restrict__ B,
                                                 float* __restrict__ C,
                                                 int M, int N, int K) {
    __shared__ float As[32][132];   // transposed A tile: As[k][m]
    __shared__ float Bs[32][132];   // Bs[k][n]
    const int tid = threadIdx.x;
    const int bm = blockIdx.x * 128;
    const int bn = blockIdx.y * 128;
    const int tx = tid & 15, ty = tid >> 4;
    float acc[2][2][4][4] = {};

    for (int k0 = 0; k0 < K; k0 += 32) {
#pragma unroll
        for (int v = 0; v < 4; ++v) {
            int row = (tid >> 3) + v * 32;
            int col = (tid & 7) * 4;
            float4 a = make_float4(0.f, 0.f, 0.f, 0.f);
            if (bm + row < M) a = *(const float4*)(A + (size_t)(bm + row) * K + k0 + col);
            As[col + 0][row] = a.x;
            As[col + 1][row] = a.y;
            As[col + 2][row] = a.z;
            As[col + 3][row] = a.w;
        }
#pragma unroll
        for (int v = 0; v < 4; ++v) {
            int kr = (tid >> 5) + v * 8;
            int col = (tid & 31) * 4;
            *(float4*)&Bs[kr][col] = *(const float4*)(B + (size_t)(k0 + kr) * N + bn + col);
        }
        __syncthreads();
#pragma unroll
        for (int kk = 0; kk < 32; ++kk) {
            float4 a0 = *(float4*)&As[kk][ty * 4];
            float4 a1 = *(float4*)&As[kk][64 + ty * 4];
            float4 b0 = *(float4*)&Bs[kk][tx * 4];
            float4 b1 = *(float4*)&Bs[kk][64 + tx * 4];
            float av[2][4] = {{a0.x, a0.y, a0.z, a0.w}, {a1.x, a1.y, a1.z, a1.w}};
            float bv[2][4] = {{b0.x, b0.y, b0.z, b0.w}, {b1.x, b1.y, b1.z, b1.w}};
#pragma unroll
            for (int ri = 0; ri < 2; ++ri)
#pragma unroll
                for (int i = 0; i < 4; ++i)
#pragma unroll
                    for (int ci = 0; ci < 2; ++ci)
#pragma unroll
                        for (int j = 0; j < 4; ++j)
                            acc[ri][ci][i][j] += av[ri][i] * bv[ci][j];
        }
        __syncthreads();
    }
#pragma unroll
    for (int ri = 0; ri < 2; ++ri)
#pragma unroll
        for (int i = 0; i < 4; ++i) {
            int row = bm + ri * 64 + ty * 4 + i;
            if (row < M) {
#pragma unroll
                for (int ci = 0; ci < 2; ++ci) {
                    float4 o = make_float4(acc[ri][ci][i][0], acc[ri][ci][i][1],
                                           acc[ri][ci][i][2], acc[ri][ci][i][3]);
                    *(float4*)(C + (size_t)row * N + bn + ci * 64 + tx * 4) = o;
                }
            }
        }
}

// ---------------- Aggregation (gather over CSR), one wave per node ----------------

template <bool RELU>
__global__ __launch_bounds__(256) void k_agg4(const float* __restrict__ xw,
                                              const float* __restrict__ dinv,
                                              const int* __restrict__ csr_src,
                                              const float* __restrict__ csr_norm,
                                              const int* __restrict__ row_start,
                                              const int* __restrict__ cnt,
                                              const float* __restrict__ bias,
                                              float* __restrict__ out, int n) {
    int node = blockIdx.x * 4 + (threadIdx.x >> 6);
    if (node >= n) return;
    int lane = threadIdx.x & 63;
    int c = lane * 4;
    float di = dinv[node];
    float4 self = *(const float4*)(xw + (size_t)node * 256 + c);
    float4 bv = *(const float4*)(bias + c);
    float sw = di * di;
    float ax = self.x * sw + bv.x;
    float ay = self.y * sw + bv.y;
    float az = self.z * sw + bv.z;
    float aw = self.w * sw + bv.w;
    int st = row_start[node];
    int m = cnt[node];
#pragma unroll 4
    for (int t = 0; t < m; ++t) {
        int s = csr_src[st + t];
        float w = csr_norm[st + t];
        float4 v = *(const float4*)(xw + (size_t)s * 256 + c);
        ax += v.x * w; ay += v.y * w; az += v.z * w; aw += v.w * w;
    }
    if (RELU) {
        ax = ax > 0.f ? ax : 0.5f * ax;
        ay = ay > 0.f ? ay : 0.5f * ay;
        az = az > 0.f ? az : 0.5f * az;
        aw = aw > 0.f ? aw : 0.5f * aw;
    }
    *(float4*)(out + (size_t)node * 256 + c) = make_float4(ax, ay, az, aw);
}

__global__ __launch_bounds__(256) void k_agg2(const float* __restrict__ xw,
                                              const float* __restrict__ dinv,
                                              const int* __restrict__ csr_src,
                                              const float* __restrict__ csr_norm,
                                              const int* __restrict__ row_start,
                                              const int* __restrict__ cnt,
                                              const float* __restrict__ bias,
                                              float* __restrict__ out, int n) {
    int node = blockIdx.x * 4 + (threadIdx.x >> 6);
    if (node >= n) return;
    int lane = threadIdx.x & 63;
    int c = lane * 2;
    float di = dinv[node];
    float2 self = *(const float2*)(xw + (size_t)node * 128 + c);
    float2 bv = *(const float2*)(bias + c);
    float sw = di * di;
    float ax = self.x * sw + bv.x;
    float ay = self.y * sw + bv.y;
    int st = row_start[node];
    int m = cnt[node];
#pragma unroll 4
    for (int t = 0; t < m; ++t) {
        int s = csr_src[st + t];
        float w = csr_norm[st + t];
        float2 v = *(const float2*)(xw + (size_t)s * 128 + c);
        ax += v.x * w; ay += v.y * w;
    }
    *(float2*)(out + (size_t)node * 128 + c) = make_float2(ax, ay);
}

// ---------------- Quantize ----------------
// Block: 128 threads = 32 nodes x 4 d-groups. h tile + centroid chunk in LDS.
// prods kept fully in registers (compile-time indexed) -> fp32-exact argmax.

template <int M_, int OFF>
__device__ __forceinline__ int do_group(const float* __restrict__ cent,
                                        const float* __restrict__ hls,
                                        float* __restrict__ cls,
                                        float* __restrict__ bal,
                                        float (&prods)[64],
                                        int tid, int hbase, int cbase, int d,
                                        bool act, int lane) {
#pragma unroll
    for (int kt = 0; kt < M_ / 8; ++kt) {
        const float* cg = cent + (size_t)(OFF + kt * 8) * 256;
#pragma unroll
        for (int it = 0; it < 16; ++it) {
            int f = it * 128 + tid;            // 2048 floats = 8 centroids x 256
            int kk = f >> 8, r = f & 255;
            cls[(r >> 6) * 516 + kk * 64 + (r & 63)] = cg[f];
        }
        __syncthreads();
        float a8[8] = {0.f, 0.f, 0.f, 0.f, 0.f, 0.f, 0.f, 0.f};
        for (int s4 = 0; s4 < 16; ++s4) {
            float4 hv = *(const float4*)&hls[hbase + s4 * 4];
#pragma unroll
            for (int u = 0; u < 8; ++u) {
                float4 cv = *(const float4*)&cls[cbase + u * 64 + s4 * 4];
                a8[u] += hv.x * cv.x + hv.y * cv.y + hv.z * cv.z + hv.w * cv.w;
            }
        }
#pragma unroll
        for (int u = 0; u < 8; ++u) prods[kt * 8 + u] = a8[u];
        __syncthreads();
    }
    // argmax (first-max, matches jnp.argmax) + softmax
    float mx = prods[0];
    int am = 0;
#pragma unroll
    for (int u = 1; u < M_; ++u)
        if (prods[u] > mx) { mx = prods[u]; am = u; }
    float Z = 0.f;
#pragma unroll
    for (int u = 0; u < M_; ++u) {
        float e2 = expf(prods[u] - mx);
        prods[u] = e2;
        Z += e2;
    }
    float invZ = 1.0f / Z;
#pragma unroll
    for (int u = 0; u < M_; ++u) {
        float p = act ? prods[u] * invZ : 0.f;
        p += __shfl_xor(p, 4);
        p += __shfl_xor(p, 8);
        p += __shfl_xor(p, 16);
        p += __shfl_xor(p, 32);
        if ((lane & 60) == 0)  // one lane per d per wave holds the 16-node sum
            atomicAdd(&bal[(OFF + u) * 4 + d], p);
    }
    return OFF + am;
}

__global__ __launch_bounds__(128) void k_quant(const float* __restrict__ h2,
                                               const float* __restrict__ cent,
                                               float* __restrict__ h3,
                                               float* __restrict__ balance_g, int n) {
    __shared__ float hls[32 * 272];   // [node][d*68 + s], padded for bank spread
    __shared__ float cls[4 * 516];    // chunk: [d][kk*64 + s]
    __shared__ float bal[480];
    const int tid = threadIdx.x;
    const int n0 = blockIdx.x * 32;
    const int nl = tid >> 2;
    const int d = tid & 3;
    const int node = n0 + nl;
    const bool act = node < n;
    const int lane = tid & 63;

    for (int i = tid; i < 480; i += 128) bal[i] = 0.f;
    // stage 32x256 h tile
#pragma unroll
    for (int it = 0; it < 16; ++it) {
        int q = it * 128 + tid;          // float4 index, 2048 total
        int row = q >> 6, col4 = q & 63;
        float4 v = make_float4(0.f, 0.f, 0.f, 0.f);
        if (n0 + row < n) v = *(const float4*)(h2 + (size_t)(n0 + row) * 256 + col4 * 4);
        int dd = col4 >> 4, s4 = col4 & 15;
        *(float4*)&hls[row * 272 + dd * 68 + s4 * 4] = v;
    }
    // (first __syncthreads inside do_group covers hls staging)

    float prods[64];
    const int hbase = nl * 272 + d * 68;
    const int cbase = d * 516;

    int km0 = do_group<8, 0>(cent, hls, cls, bal, prods, tid, hbase, cbase, d, act, lane);
    int km1 = do_group<16, 8>(cent, hls, cls, bal, prods, tid, hbase, cbase, d, act, lane);
    int km2 = do_group<32, 24>(cent, hls, cls, bal, prods, tid, hbase, cbase, d, act, lane);
    int km3 = do_group<64, 56>(cent, hls, cls, bal, prods, tid, hbase, cbase, d, act, lane);

    if (act) {
        const float* c0 = cent + (size_t)km0 * 256 + d * 64;
        const float* c1 = cent + (size_t)km1 * 256 + d * 64;
        const float* c2 = cent + (size_t)km2 * 256 + d * 64;
        const float* c3 = cent + (size_t)km3 * 256 + d * 64;
        float* o = h3 + (size_t)node * 256 + d * 64;
#pragma unroll
        for (int s4 = 0; s4 < 16; ++s4) {
            float4 v0 = *(const float4*)(c0 + s4 * 4);
            float4 v1 = *(const float4*)(c1 + s4 * 4);
            float4 v2 = *(const float4*)(c2 + s4 * 4);
            float4 v3 = *(const float4*)(c3 + s4 * 4);
            float4 hv = *(const float4*)&hls[hbase + s4 * 4];
            float4 r;
            r.x = hv.x + fmaxf(fmaxf(v0.x, v1.x), fmaxf(v2.x, v3.x));
            r.y = hv.y + fmaxf(fmaxf(v0.y, v1.y), fmaxf(v2.y, v3.y));
            r.z = hv.z + fmaxf(fmaxf(v0.z, v1.z), fmaxf(v2.z, v3.z));
            r.w = hv.w + fmaxf(fmaxf(v0.w, v1.w), fmaxf(v2.w, v3.w));
            *(float4*)(o + s4 * 4) = r;
        }
    }
    __syncthreads();
    for (int i = tid; i < 480; i += 128) atomicAdd(&balance_g[i], bal[i]);
}

__global__ void k_reg(const float* __restrict__ balance_g, float* __restrict__ out_reg,
                      float inv_n) {
    __shared__ float red[512];
    int tid = threadIdx.x;
    float v = 0.f;
    if (tid < 480) {
        int k = tid >> 2;
        float target = (k < 8) ? 0.125f : (k < 24) ? 0.0625f : (k < 56) ? 0.03125f : 0.015625f;
        float b = balance_g[tid] * inv_n;
        float df = b - target;
        v = df * df;
    }
    red[tid] = v;
    __syncthreads();
    for (int s = 256; s > 0; s >>= 1) {
        if (tid < s) red[tid] += red[tid + s];
        __syncthreads();
    }
    if (tid == 0) *out_reg = sqrtf(red[0]);
}

// ---------------- host launch ----------------

extern "C" void kernel_launch(void* const* d_in, const int* in_sizes, int n_in,
                              void* d_out, int out_size, void* d_ws, size_t ws_size,
                              hipStream_t stream) {
    const float* x    = (const float*)d_in[0];
    const int*   ei   = (const int*)d_in[1];
    const float* W0   = (const float*)d_in[2];
    const float* b0   = (const float*)d_in[3];
    const float* W1   = (const float*)d_in[4];
    const float* b1   = (const float*)d_in[5];
    const float* W2   = (const float*)d_in[6];
    const float* b2   = (const float*)d_in[7];
    const float* cent = (const float*)d_in[8];
    const int n = in_sizes[0] / 256;
    const int e = in_sizes[1] / 2;
    const int* src = ei;
    const int* dst = ei + e;
    float* out = (float*)d_out;

    char* w = (char*)d_ws;
    float* bufA = (float*)w;      w += (size_t)n * 256 * 4;
    float* bufB = (float*)w;      w += (size_t)n * 256 * 4;
    float* dinv = (float*)w;      w += (size_t)n * 4;
    int* cnt = (int*)w;           w += (size_t)n * 4;
    int* row_start = (int*)w;     w += (size_t)n * 4;
    int* cursor = (int*)w;        w += (size_t)n * 4;
    int* csr_src = (int*)w;       w += (size_t)e * 4;
    float* csr_norm = (float*)w;  w += (size_t)e * 4;
    int* counter = (int*)w;       w += 256;
    float* balance = (float*)w;   w += 480 * 4;

    const int tb = 256;
    k_init<<<(n + tb - 1) / tb, tb, 0, stream>>>(cnt, cursor, counter, balance, n);
    k_count<<<(e + tb - 1) / tb, tb, 0, stream>>>(dst, cnt, e);
    k_dinv<<<(n + tb - 1) / tb, tb, 0, stream>>>(cnt, dinv, n);
    k_alloc<<<(n + tb - 1) / tb, tb, 0, stream>>>(cnt, row_start, counter, n);
    k_fill<<<(e + tb - 1) / tb, tb, 0, stream>>>(src, dst, dinv, row_start, cursor,
                                                 csr_src, csr_norm, e);

    dim3 g1((n + 127) / 128, 2);
    k_gemm<<<g1, 256, 0, stream>>>(x, W0, bufA, n, 256, 256);
    k_agg4<true><<<(n + 3) / 4, 256, 0, stream>>>(bufA, dinv, csr_src, csr_norm,
                                                  row_start, cnt, b0, bufB, n);
    k_gemm<<<g1, 256, 0, stream>>>(bufB, W1, bufA, n, 256, 256);
    k_agg4<true><<<(n + 3) / 4, 256, 0, stream>>>(bufA, dinv, csr_src, csr_norm,
                                                  row_start, cnt, b1, bufB, n);
    k_quant<<<(n + 31) / 32, 128, 0, stream>>>(bufB, cent, bufA, balance, n);

    dim3 g3((n + 127) / 128, 1);
    k_gemm<<<g3, 256, 0, stream>>>(bufA, W2, bufB, n, 128, 256);
    k_agg2<<<(n + 3) / 4, 256, 0, stream>>>(bufB, dinv, csr_src, csr_norm,
                                            row_start, cnt, b2, out, n);
    k_reg<<<1, 512, 0, stream>>>(balance, out + (size_t)n * 128, 1.0f / (float)n);
}